// Round 10
// baseline (52.544 us; speedup 1.0000x reference)
//
#include <hip/hip_runtime.h>
#include <hip/hip_bf16.h>

typedef _Float16 f16;
typedef f16 f16x2 __attribute__((ext_vector_type(2)));
typedef f16 f16x4 __attribute__((ext_vector_type(4)));
typedef f16 f16x8 __attribute__((ext_vector_type(8)));
typedef float f32x4 __attribute__((ext_vector_type(4)));

constexpr int B_  = 4;
constexpr int H_  = 128;
constexpr int W_  = 128;
constexpr int C_  = 64;
constexpr int NH_ = 4;
constexpr int D_  = 16;
constexpr int KK_ = 25;

constexpr int TW_  = 8, TH_ = 8;
constexpr int HWID = 12, HHEI = 12;
constexpr int NPX  = HHEI * HWID;          // 144 halo pixels
// LDS layout:
//   [0    , 18432) abuf  [144][64] f16, chunk-XOR swizzled; staged ref -> r in-place
//   [18432, 28672) qbuf  [4 heads][64 px][20 f16] (16 used, stride 20 = 40B)
//   [28672, 35584) pbuf  [64][27] f32 head-summed probs (ds_add)
//   [35584, 39680) msbuf [2][4][64] float2 (m,s) exchange
constexpr int QSTR  = 20;                  // f16 units per pixel in qbuf
constexpr int QOFF  = NPX * 64 * 2;        // 18432
constexpr int POFF  = QOFF + NH_ * 64 * QSTR * 2;   // 28672
constexpr int MSOFF = POFF + 64 * 27 * 4;  // 35584
constexpr int SMEM  = MSOFF + 4096;        // 39680 <= 40960 -> 4 blocks/CU
constexpr int PSTR  = 27;                  // f32 units

#if __has_builtin(__builtin_amdgcn_fdot2)
#define FDOT2(a, b, c) __builtin_amdgcn_fdot2((a), (b), (c), false)
#else
#define FDOT2(a, b, c) fmaf((float)(a)[1], (float)(b)[1], fmaf((float)(a)[0], (float)(b)[0], (c)))
#endif

__device__ __forceinline__ int div12(int x) { return (x * 171) >> 11; }  // exact for 0..143

__global__ __launch_bounds__(512, 8) void rl8mh10(
    const float* __restrict__ mainp, const float* __restrict__ refp,
    const float* __restrict__ wmain, const float* __restrict__ wref,
    float* __restrict__ out)
{
    __shared__ __align__(16) unsigned char smraw[SMEM];
    f16*    abuf  = (f16*)smraw;
    f16*    qbuf  = (f16*)(smraw + QOFF);
    float*  pbuf  = (float*)(smraw + POFF);
    float2* msbuf = (float2*)(smraw + MSOFF);

    const int tid = threadIdx.x;
    const int l   = tid & 63;
    const int wid = __builtin_amdgcn_readfirstlane(tid >> 6);  // 0..7
    const int n   = wid & 3;    // head
    const int h   = wid >> 2;   // half
    const int row = l & 15;
    const int kg  = l >> 4;

    // XCD-chunked swizzle (bijective, 256 % 8 == 0)
    const int bid = blockIdx.y * 16 + blockIdx.x;
    const int swz = (bid & 7) * 32 + (bid >> 3);
    const int x0 = (swz & 15) * TW_;
    const int y0 = (swz >> 4) * TH_;
    const int b  = blockIdx.z;
    const float* mainb = mainp + ((size_t)b * H_) * W_ * C_;
    const float* refb  = refp  + ((size_t)b * H_) * W_ * C_;

    // ---- weight fragments (A-operand of swapped MFMA), issued early ----
    f16x8 am[2], ar[2];
    {
        const float* wm = wmain + n * C_ * D_;
        const float* wr = wref  + n * C_ * D_;
        #pragma unroll
        for (int s = 0; s < 2; ++s) {
            union { f16x8 v; f16 e[8]; } um, ur;
            #pragma unroll
            for (int i = 0; i < 8; ++i) {
                int k = (s * 32 + kg * 8 + i) * D_ + row;
                um.e[i] = (f16)wm[k];
                ur.e[i] = (f16)wr[k];
            }
            am[s] = um.v; ar[s] = ur.v;
        }
    }

    // ---- Phase 0a: stage ref halo -> abuf (coalesced, f32->f16, chunk XOR) ----
    for (int j = tid; j < NPX * 16; j += 512) {
        int hp = j >> 4, c4 = j & 15;
        int hy = div12(hp), hx = hp - hy * HWID;
        int gy = y0 + hy - 2, gx = x0 + hx - 2;
        float4 v = make_float4(0.f, 0.f, 0.f, 0.f);
        if ((unsigned)gy < (unsigned)H_ && (unsigned)gx < (unsigned)W_)
            v = *(const float4*)(refb + ((size_t)gy * W_ + gx) * C_ + c4 * 4);
        f16x4 h4 = {(f16)v.x, (f16)v.y, (f16)v.z, (f16)v.w};
        int off = hp * 64 + ((((c4 >> 1) ^ (hp & 7)) << 3) | ((c4 & 1) << 2));
        *(f16x4*)(abuf + off) = h4;
    }
    // ---- Phase 0b: zero pbuf (fenced by bar1 << bar4 before ds_add use) ----
    if (tid < (64 * PSTR) / 4) ((f32x4*)pbuf)[tid] = f32x4{0.f, 0.f, 0.f, 0.f};

    // ---- Phase 0c: q projection DIRECT from global (per-head qbuf!) ----
    {
        #pragma unroll
        for (int ti = 0; ti < 2; ++ti) {
            int t  = ti * 2 + h;             // h=0: tiles 0,2 ; h=1: tiles 1,3
            int px = t * 16 + row;
            int gy = y0 + (px >> 3), gx = x0 + (px & 7);
            const float* src = mainb + ((size_t)gy * W_ + gx) * C_ + kg * 8;
            f32x4 acc = {0.f, 0.f, 0.f, 0.f};
            #pragma unroll
            for (int s = 0; s < 2; ++s) {
                float4 v0 = *(const float4*)(src + s * 32);
                float4 v1 = *(const float4*)(src + s * 32 + 4);
                union { f16x8 v; f16 e[8]; } u;
                u.e[0]=(f16)v0.x; u.e[1]=(f16)v0.y; u.e[2]=(f16)v0.z; u.e[3]=(f16)v0.w;
                u.e[4]=(f16)v1.x; u.e[5]=(f16)v1.y; u.e[6]=(f16)v1.z; u.e[7]=(f16)v1.w;
                acc = __builtin_amdgcn_mfma_f32_16x16x32_f16(am[s], u.v, acc, 0, 0, 0);
            }
            // lane holds q[n][px][kg*4 .. kg*4+3]
            f16x4 q4 = {(f16)acc[0], (f16)acc[1], (f16)acc[2], (f16)acc[3]};
            *(f16x4*)(qbuf + (n * 64 + px) * QSTR + kg * 4) = q4;
        }
    }
    __syncthreads();   // bar1: abuf + qbuf complete

    // ---- Phase 1: r projection from abuf into registers (lane = pixel) ----
    auto proj_r = [&](int t) -> f16x4 {
        int px = t * 16 + row;
        const f16* rp = abuf + px * 64;
        f16x8 B0 = *(const f16x8*)(rp + (((kg     ^ (px & 7)) << 3)));
        f16x8 B1 = *(const f16x8*)(rp + ((((kg+4) ^ (px & 7)) << 3)));
        f32x4 acc = {0.f, 0.f, 0.f, 0.f};
        acc = __builtin_amdgcn_mfma_f32_16x16x32_f16(ar[0], B0, acc, 0, 0, 0);
        acc = __builtin_amdgcn_mfma_f32_16x16x32_f16(ar[1], B1, acc, 0, 0, 0);
        return f16x4{(f16)acc[0], (f16)acc[1], (f16)acc[2], (f16)acc[3]};
    };
    f16x4 racc0, racc1, racc2, racc3, racc4;
    if (h == 0) {
        racc0 = proj_r(0); racc1 = proj_r(2); racc2 = proj_r(4);
        racc3 = proj_r(6); racc4 = proj_r(8);
    } else {
        racc0 = proj_r(1); racc1 = proj_r(3); racc2 = proj_r(5);
        racc3 = proj_r(7);
    }
    __syncthreads();   // bar2: all abuf reads done -> safe to overwrite

    // ---- Phase 2: write r in-place (lane holds d = kg*4..+3 of its pixel) ----
    auto wrout = [&](int t, f16x4 v) {
        int px = t * 16 + row;
        int c16 = (n << 1) | (kg >> 1);
        int off = px * 64 + (((c16 ^ (px & 7)) << 3) | ((kg & 1) << 2));
        *(f16x4*)(abuf + off) = v;
    };
    if (h == 0) {
        wrout(0, racc0); wrout(2, racc1); wrout(4, racc2);
        wrout(6, racc3); wrout(8, racc4);
    } else {
        wrout(1, racc0); wrout(3, racc1); wrout(5, racc2); wrout(7, racc3);
    }
    __syncthreads();   // bar3: rbuf ready

    // ---- per-thread q fragment (pixel = lane, head = n) ----
    const int py  = l >> 3;
    const int pxx = l & 7;
    union { f16x4 v4[4]; f16x2 v2[8]; } qu;
    {
        const f16* qp = qbuf + (n * 64 + l) * QSTR;
        qu.v4[0] = *(const f16x4*)(qp);
        qu.v4[1] = *(const f16x4*)(qp + 4);
        qu.v4[2] = *(const f16x4*)(qp + 8);
        qu.v4[3] = *(const f16x4*)(qp + 12);
    }
    const f16x2* q2 = qu.v2;

    // ---- logits: half h computes 13 (or 12) offsets ----
    float lg[13];
    auto do_lg = [&](int idx, int k) {
        int ky = k / 5, kx = k % 5;              // compile-time
        int np = (py + ky) * 12 + pxx + kx;      // neighbor halo pixel
        const f16* rp = abuf + np * 64;
        f16x8 r0 = *(const f16x8*)(rp + ((((n << 1) | 0) ^ (np & 7)) << 3));
        f16x8 r1 = *(const f16x8*)(rp + ((((n << 1) | 1) ^ (np & 7)) << 3));
        const f16x2* r2a = (const f16x2*)&r0;
        const f16x2* r2b = (const f16x2*)&r1;
        float a = 0.f;
        #pragma unroll
        for (int j = 0; j < 4; ++j) a = FDOT2(q2[j], r2a[j], a);
        #pragma unroll
        for (int j = 0; j < 4; ++j) a = FDOT2(q2[4 + j], r2b[j], a);
        lg[idx] = a;
    };
    if (h == 0) {
        do_lg(0,0);  do_lg(1,1);  do_lg(2,2);  do_lg(3,3);  do_lg(4,4);
        do_lg(5,5);  do_lg(6,6);  do_lg(7,7);  do_lg(8,8);  do_lg(9,9);
        do_lg(10,10); do_lg(11,11); do_lg(12,12);
    } else {
        do_lg(0,13); do_lg(1,14); do_lg(2,15); do_lg(3,16); do_lg(4,17);
        do_lg(5,18); do_lg(6,19); do_lg(7,20); do_lg(8,21); do_lg(9,22);
        do_lg(10,23); do_lg(11,24);
        lg[12] = -1e30f;   // dead slot -> exp()=0
    }

    // ---- online split softmax: single (m,s) exchange ----
    float mloc = lg[0];
    #pragma unroll
    for (int k = 1; k < 13; ++k) mloc = fmaxf(mloc, lg[k]);

    float s = 0.f;
    f16x2 pk[7];
    #pragma unroll
    for (int j = 0; j < 6; ++j) {
        float e0 = __expf(lg[2*j]   - mloc);
        float e1 = __expf(lg[2*j+1] - mloc);
        s += e0 + e1;
        pk[j] = f16x2{(f16)e0, (f16)e1};
    }
    {
        float e12 = __expf(lg[12] - mloc);
        s += e12;
        pk[6] = f16x2{(f16)e12, (f16)0.f};
    }
    msbuf[(h * 4 + n) * 64 + l] = make_float2(mloc, s);
    __syncthreads();   // bar4
    float2 o = msbuf[((1 - h) * 4 + n) * 64 + l];
    float m    = fmaxf(mloc, o.x);
    float sc   = __expf(mloc - m);
    float osc  = __expf(o.x  - m);
    float inv  = sc / (s * sc + o.y * osc);

    // ---- accumulate probs across heads via LDS atomics ----
    {
        float* dst = &pbuf[l * PSTR + h * 13];
        #pragma unroll
        for (int j = 0; j < 6; ++j) {
            atomicAdd(&dst[2*j],     (float)pk[j][0] * inv);
            atomicAdd(&dst[2*j + 1], (float)pk[j][1] * inv);
        }
        if (h == 0) atomicAdd(&dst[12], (float)pk[6][0] * inv);
    }
    __syncthreads();   // bar5

    // ---- final: scale + store ----
    for (int i = tid; i < TW_ * TH_ * KK_; i += 512) {
        int p2 = i / KK_;
        int k  = i - p2 * KK_;
        float v = 0.25f * pbuf[p2 * PSTR + k];
        out[(((size_t)b * H_ + (y0 + (p2 >> 3))) * W_ + (x0 + (p2 & 7))) * KK_ + k] = v;
    }
}

extern "C" void kernel_launch(void* const* d_in, const int* in_sizes, int n_in,
                              void* d_out, int out_size, void* d_ws, size_t ws_size,
                              hipStream_t stream) {
    const float* mainp = (const float*)d_in[0];
    const float* refp  = (const float*)d_in[1];
    const float* wmain = (const float*)d_in[2];
    const float* wref  = (const float*)d_in[3];
    float* outp = (float*)d_out;

    dim3 grid(W_ / TW_, H_ / TH_, B_);
    rl8mh10<<<grid, dim3(512), 0, stream>>>(mainp, refp, wmain, wref, outp);
}

// Round 11
// 19.054 us; speedup vs baseline: 2.7577x; 2.7577x over previous
//
#include <hip/hip_runtime.h>
#include <hip/hip_bf16.h>

typedef _Float16 f16;
typedef f16 f16x2 __attribute__((ext_vector_type(2)));
typedef f16 f16x4 __attribute__((ext_vector_type(4)));
typedef f16 f16x8 __attribute__((ext_vector_type(8)));
typedef float f32x4 __attribute__((ext_vector_type(4)));

constexpr int B_  = 4;
constexpr int H_  = 128;
constexpr int W_  = 128;
constexpr int C_  = 64;
constexpr int NH_ = 4;
constexpr int D_  = 16;
constexpr int KK_ = 25;

constexpr int TW_  = 8, TH_ = 8;
constexpr int HWID = 12, HHEI = 12;
constexpr int NPX  = HHEI * HWID;          // 144 halo pixels
// LDS layout (R8 layout, proven 18.9us):
//   [0    , 18432) abuf  [144][64] f16, chunk-XOR swizzled; staged ref -> r in-place
//   [18432, 26624) mabuf [64][64]  f16; staged main -> q in-place
//   [0    , 27648) xbuf  f32 prob exchange (aliases the above, fenced)
//   [27648, 31744) msbuf [2][4][64] float2 (m,s)
constexpr int MOFF  = NPX * 64 * 2;        // 18432
constexpr int MSOFF = 27648;
constexpr int SMEM  = 31744;               // <= 40960 -> 4 blocks/CU (wave cap)
constexpr int PSTRIDE = KK_ + 2;           // 27 (odd -> conflict-free)
constexpr int PSLAB   = 64 * PSTRIDE;      // 1728 f32

#if __has_builtin(__builtin_amdgcn_fdot2)
#define FDOT2(a, b, c) __builtin_amdgcn_fdot2((a), (b), (c), false)
#else
#define FDOT2(a, b, c) fmaf((float)(a)[1], (float)(b)[1], fmaf((float)(a)[0], (float)(b)[0], (c)))
#endif

__device__ __forceinline__ int div12(int x) { return (x * 171) >> 11; }  // exact for 0..143

__global__ __launch_bounds__(512, 8) void rl8mh11(
    const float* __restrict__ mainp, const float* __restrict__ refp,
    const float* __restrict__ wmain, const float* __restrict__ wref,
    float* __restrict__ out)
{
    __shared__ __align__(16) unsigned char smraw[SMEM];
    f16*    abuf  = (f16*)smraw;             // staged ref halo -> rbuf in-place
    f16*    mabuf = (f16*)(smraw + MOFF);    // staged main     -> qbuf in-place
    float*  xbuf  = (float*)smraw;
    float2* msbuf = (float2*)(smraw + MSOFF);

    const int tid = threadIdx.x;
    const int l   = tid & 63;
    const int wid = __builtin_amdgcn_readfirstlane(tid >> 6);  // 0..7
    const int n   = wid & 3;    // head
    const int h   = wid >> 2;   // half
    const int row = l & 15;
    const int kg  = l >> 4;

    // XCD-chunked swizzle (bijective, 256 % 8 == 0)
    const int bid = blockIdx.y * 16 + blockIdx.x;
    const int swz = (bid & 7) * 32 + (bid >> 3);
    const int x0 = (swz & 15) * TW_;
    const int y0 = (swz >> 4) * TH_;
    const int b  = blockIdx.z;
    const float* mainb = mainp + ((size_t)b * H_) * W_ * C_;
    const float* refb  = refp  + ((size_t)b * H_) * W_ * C_;

    // ---- Phase 0: staging with BATCHED loads (issue all 7, then write all) ----
    float4 hv[5];
    int    hoff[5];
    #pragma unroll
    for (int t = 0; t < 5; ++t) {
        int j  = tid + t * 512;            // t<4 always < 2304; t=4 valid if tid<256
        bool valid = (j < NPX * 16);
        int hp = j >> 4, c4 = j & 15;
        int hy = div12(hp & 255), hx = hp - hy * HWID;
        int gy = y0 + hy - 2, gx = x0 + hx - 2;
        hv[t] = make_float4(0.f, 0.f, 0.f, 0.f);
        if (valid && (unsigned)gy < (unsigned)H_ && (unsigned)gx < (unsigned)W_)
            hv[t] = *(const float4*)(refb + ((size_t)gy * W_ + gx) * C_ + c4 * 4);
        hoff[t] = hp * 64 + ((((c4 >> 1) ^ (hp & 7)) << 3) | ((c4 & 1) << 2));
    }
    float4 mv[2];
    int    moff[2];
    #pragma unroll
    for (int t = 0; t < 2; ++t) {
        int j  = tid + t * 512;            // < 1024 always
        int px = j >> 4, c4 = j & 15;
        int gy = y0 + (px >> 3), gx = x0 + (px & 7);
        mv[t] = *(const float4*)(mainb + ((size_t)gy * W_ + gx) * C_ + c4 * 4);
        moff[t] = px * 64 + ((((c4 >> 1) ^ (px & 7)) << 3) | ((c4 & 1) << 2));
    }
    #pragma unroll
    for (int t = 0; t < 5; ++t) {
        if (t < 4 || tid < (NPX * 16 - 4 * 512)) {
            f16x4 h4 = {(f16)hv[t].x, (f16)hv[t].y, (f16)hv[t].z, (f16)hv[t].w};
            *(f16x4*)(abuf + hoff[t]) = h4;
        }
    }
    #pragma unroll
    for (int t = 0; t < 2; ++t) {
        f16x4 h4 = {(f16)mv[t].x, (f16)mv[t].y, (f16)mv[t].z, (f16)mv[t].w};
        *(f16x4*)(mabuf + moff[t]) = h4;
    }
    __syncthreads();   // bar1

    // ---- weight fragment build (A-operand of swapped MFMA), AFTER staging ----
    auto build_w = [&](const float* wsrc, f16x8* A) {
        const float* w = wsrc + n * C_ * D_;
        #pragma unroll
        for (int s = 0; s < 2; ++s) {
            union { f16x8 v; f16 e[8]; } u;
            #pragma unroll
            for (int i = 0; i < 8; ++i)
                u.e[i] = (f16)w[(s * 32 + kg * 8 + i) * D_ + row];
            A[s] = u.v;
        }
    };

    // ---- Phase 1: projections into registers (swapped MFMA: lane = pixel) ----
    auto proj = [&](const f16* src, int t, const f16x8* A) -> f16x4 {
        int px = t * 16 + row;
        const f16* rp = src + px * 64;
        f16x8 B0 = *(const f16x8*)(rp + (((kg     ^ (px & 7)) << 3)));
        f16x8 B1 = *(const f16x8*)(rp + ((((kg+4) ^ (px & 7)) << 3)));
        f32x4 acc = {0.f, 0.f, 0.f, 0.f};
        acc = __builtin_amdgcn_mfma_f32_16x16x32_f16(A[0], B0, acc, 0, 0, 0);
        acc = __builtin_amdgcn_mfma_f32_16x16x32_f16(A[1], B1, acc, 0, 0, 0);
        return f16x4{(f16)acc[0], (f16)acc[1], (f16)acc[2], (f16)acc[3]};
    };
    f16x4 racc0, racc1, racc2, racc3, racc4, qacc0, qacc1;
    {
        f16x8 ar[2];
        build_w(wref, ar);
        if (h == 0) {
            racc0 = proj(abuf, 0, ar); racc1 = proj(abuf, 2, ar);
            racc2 = proj(abuf, 4, ar); racc3 = proj(abuf, 6, ar);
            racc4 = proj(abuf, 8, ar);
        } else {
            racc0 = proj(abuf, 1, ar); racc1 = proj(abuf, 3, ar);
            racc2 = proj(abuf, 5, ar); racc3 = proj(abuf, 7, ar);
        }
    }
    {
        f16x8 am[2];
        build_w(wmain, am);
        if (h == 0) { qacc0 = proj(mabuf, 0, am); qacc1 = proj(mabuf, 2, am); }
        else        { qacc0 = proj(mabuf, 1, am); qacc1 = proj(mabuf, 3, am); }
    }
    __syncthreads();   // bar2: all staging reads done -> safe to overwrite

    // ---- Phase 2: write r/q in-place (lane holds d = kg*4..+3 of its pixel) ----
    auto wrout = [&](f16* dst, int t, f16x4 v) {
        int px = t * 16 + row;
        int c16 = (n << 1) | (kg >> 1);
        int off = px * 64 + (((c16 ^ (px & 7)) << 3) | ((kg & 1) << 2));
        *(f16x4*)(dst + off) = v;
    };
    if (h == 0) {
        wrout(abuf, 0, racc0); wrout(abuf, 2, racc1); wrout(abuf, 4, racc2);
        wrout(abuf, 6, racc3); wrout(abuf, 8, racc4);
        wrout(mabuf, 0, qacc0); wrout(mabuf, 2, qacc1);
    } else {
        wrout(abuf, 1, racc0); wrout(abuf, 3, racc1); wrout(abuf, 5, racc2);
        wrout(abuf, 7, racc3);
        wrout(mabuf, 1, qacc0); wrout(mabuf, 3, qacc1);
    }
    __syncthreads();   // bar3

    // ---- per-thread q fragment (pixel = lane) ----
    const int py  = l >> 3;
    const int pxx = l & 7;
    f16x8 q0 = *(const f16x8*)(mabuf + l * 64 + ((((n << 1) | 0) ^ (l & 7)) << 3));
    f16x8 q1 = *(const f16x8*)(mabuf + l * 64 + ((((n << 1) | 1) ^ (l & 7)) << 3));
    const f16x2* q2a = (const f16x2*)&q0;
    const f16x2* q2b = (const f16x2*)&q1;

    // ---- logits: half h computes 13 (or 12) offsets ----
    float lg[13];
    auto do_lg = [&](int idx, int k) {
        int ky = k / 5, kx = k % 5;              // compile-time
        int np = (py + ky) * 12 + pxx + kx;      // neighbor halo pixel
        const f16* rp = abuf + np * 64;
        f16x8 r0 = *(const f16x8*)(rp + ((((n << 1) | 0) ^ (np & 7)) << 3));
        f16x8 r1 = *(const f16x8*)(rp + ((((n << 1) | 1) ^ (np & 7)) << 3));
        const f16x2* r2a = (const f16x2*)&r0;
        const f16x2* r2b = (const f16x2*)&r1;
        float a = 0.f;
        #pragma unroll
        for (int j = 0; j < 4; ++j) a = FDOT2(q2a[j], r2a[j], a);
        #pragma unroll
        for (int j = 0; j < 4; ++j) a = FDOT2(q2b[j], r2b[j], a);
        lg[idx] = a;
    };
    if (h == 0) {
        do_lg(0,0);  do_lg(1,1);  do_lg(2,2);  do_lg(3,3);  do_lg(4,4);
        do_lg(5,5);  do_lg(6,6);  do_lg(7,7);  do_lg(8,8);  do_lg(9,9);
        do_lg(10,10); do_lg(11,11); do_lg(12,12);
    } else {
        do_lg(0,13); do_lg(1,14); do_lg(2,15); do_lg(3,16); do_lg(4,17);
        do_lg(5,18); do_lg(6,19); do_lg(7,20); do_lg(8,21); do_lg(9,22);
        do_lg(10,23); do_lg(11,24);
        lg[12] = -1e30f;   // dead slot -> exp()=0
    }

    // ---- online split softmax: single (m,s) exchange ----
    float mloc = lg[0];
    #pragma unroll
    for (int k = 1; k < 13; ++k) mloc = fmaxf(mloc, lg[k]);

    float s = 0.f;
    f16x2 pk[7];                       // exp values packed (13 -> 7 regs)
    #pragma unroll
    for (int j = 0; j < 6; ++j) {
        float e0 = __expf(lg[2*j]   - mloc);
        float e1 = __expf(lg[2*j+1] - mloc);
        s += e0 + e1;
        pk[j] = f16x2{(f16)e0, (f16)e1};
    }
    {
        float e12 = __expf(lg[12] - mloc);
        s += e12;
        pk[6] = f16x2{(f16)e12, (f16)0.f};
    }
    msbuf[(h * 4 + n) * 64 + l] = make_float2(mloc, s);
    __syncthreads();   // bar4
    float2 o = msbuf[((1 - h) * 4 + n) * 64 + l];
    float m    = fmaxf(mloc, o.x);
    float sc   = __expf(mloc - m);
    float osc  = __expf(o.x  - m);
    float inv  = sc / (s * sc + o.y * osc);

    // ---- write probs (xbuf aliases abuf/mabuf; all reads fenced by bar4) ----
    {
        float* dst = &xbuf[n * PSLAB + l * PSTRIDE + h * 13];
        #pragma unroll
        for (int j = 0; j < 6; ++j) {
            dst[2*j]     = (float)pk[j][0] * inv;
            dst[2*j + 1] = (float)pk[j][1] * inv;
        }
        if (h == 0) dst[12] = (float)pk[6][0] * inv;
    }
    __syncthreads();   // bar5

    // ---- head-average + store ----
    for (int i = tid; i < TW_ * TH_ * KK_; i += 512) {
        int p2 = i / KK_;
        int k  = i - p2 * KK_;
        int off = p2 * PSTRIDE + k;
        float v = 0.25f * (xbuf[off] + xbuf[PSLAB + off] + xbuf[2 * PSLAB + off] + xbuf[3 * PSLAB + off]);
        out[(((size_t)b * H_ + (y0 + (p2 >> 3))) * W_ + (x0 + (p2 & 7))) * KK_ + k] = v;
    }
}

extern "C" void kernel_launch(void* const* d_in, const int* in_sizes, int n_in,
                              void* d_out, int out_size, void* d_ws, size_t ws_size,
                              hipStream_t stream) {
    const float* mainp = (const float*)d_in[0];
    const float* refp  = (const float*)d_in[1];
    const float* wmain = (const float*)d_in[2];
    const float* wref  = (const float*)d_in[3];
    float* outp = (float*)d_out;

    dim3 grid(W_ / TW_, H_ / TH_, B_);
    rl8mh11<<<grid, dim3(512), 0, stream>>>(mainp, refp, wmain, wref, outp);
}